// Round 1
// baseline (3086.661 us; speedup 1.0000x reference)
//
#include <hip/hip_runtime.h>

#define NN 50000
#define HD 64
#define BN_EPS 1e-5f

// ---------------- scatter-add: agg[dst] += x[src] ----------------
// LOGF4: log2(threads per edge); each thread handles 4 consecutive feats.
template<int LOGF4>
__global__ __launch_bounds__(256) void scatter_add_kernel(
    const float* __restrict__ x, const int* __restrict__ ei,
    float* __restrict__ agg, int E)
{
    const int F4 = 1 << LOGF4;
    const int F  = F4 * 4;
    int t = blockIdx.x * 256 + threadIdx.x;
    if (t >= (E << LOGF4)) return;
    int e = t >> LOGF4;
    int c = (t & (F4 - 1)) << 2;
    int s = ei[e];
    int d = ei[E + e];
    const float4 v = *(const float4*)(x + s * F + c);
    float* a = agg + d * F + c;
    atomicAdd(a + 0, v.x);
    atomicAdd(a + 1, v.y);
    atomicAdd(a + 2, v.z);
    atomicAdd(a + 3, v.w);
}

// ---------------- fused (1+eps)*x + agg -> Linear-ReLU-Linear-ReLU + BN stats ----------------
// Block = 256 threads = 4 rows x 64 cols. Weights staged in LDS.
template<int F>
__global__ __launch_bounds__(256) void gin_mlp_kernel(
    const float* __restrict__ x, const float* __restrict__ agg,
    const float* __restrict__ eps_p,
    const float* __restrict__ wa, const float* __restrict__ ba,
    const float* __restrict__ wb, const float* __restrict__ bb,
    float* __restrict__ h_raw, float* __restrict__ stats /*[0:64]=sum [64:128]=sumsq*/)
{
    __shared__ float s_wa[F * 64];
    __shared__ float s_wb[64 * 64];
    __shared__ float s_h[4][F];
    __shared__ float s_t[4][64];

    for (int i = threadIdx.x; i < F * 64; i += 256) s_wa[i] = wa[i];
    for (int i = threadIdx.x; i < 64 * 64; i += 256) s_wb[i] = wb[i];

    const float eps1 = 1.0f + eps_p[0];
    const int r = threadIdx.x >> 6;   // 0..3
    const int c = threadIdx.x & 63;   // 0..63
    const float ba_c = ba[c];
    const float bb_c = bb[c];
    float sum = 0.0f, sumsq = 0.0f;
    __syncthreads();

    for (int row0 = blockIdx.x * 4; row0 < NN; row0 += gridDim.x * 4) {
        __syncthreads();  // protect s_h/s_t reuse from previous iter
        // stage hpre = (1+eps)*x + agg for 4 rows
        for (int i = threadIdx.x; i < 4 * F; i += 256) {
            int rr = i / F;
            int kk = i % F;
            int row = row0 + rr;
            s_h[rr][kk] = eps1 * x[row * F + kk] + agg[row * F + kk];
        }
        __syncthreads();
        // GEMM1 + ReLU
        float acc = ba_c;
        #pragma unroll 8
        for (int k = 0; k < F; k++)
            acc = fmaf(s_h[r][k], s_wa[k * 64 + c], acc);
        s_t[r][c] = fmaxf(acc, 0.0f);
        __syncthreads();
        // GEMM2 + ReLU
        float acc2 = bb_c;
        #pragma unroll 8
        for (int k = 0; k < 64; k++)
            acc2 = fmaf(s_t[r][k], s_wb[k * 64 + c], acc2);
        float h = fmaxf(acc2, 0.0f);
        h_raw[row0 * 64 + r * 64 + c] = h;
        sum += h;
        sumsq += h * h;
    }

    // reduce BN partials: 4 r-slots per column, then 2 atomics/column/block
    __syncthreads();
    s_t[r][c] = sum;
    __syncthreads();
    if (r == 0) {
        float s0 = s_t[0][c] + s_t[1][c] + s_t[2][c] + s_t[3][c];
        atomicAdd(&stats[c], s0);
    }
    __syncthreads();
    s_t[r][c] = sumsq;
    __syncthreads();
    if (r == 0) {
        float s0 = s_t[0][c] + s_t[1][c] + s_t[2][c] + s_t[3][c];
        atomicAdd(&stats[64 + c], s0);
    }
}

// ---------------- BN apply + ReLU ----------------
__global__ __launch_bounds__(256) void bn_relu_kernel(
    const float* __restrict__ h_raw, const float* __restrict__ stats,
    const float* __restrict__ g, const float* __restrict__ be,
    float* __restrict__ out)
{
    int i = blockIdx.x * 256 + threadIdx.x;
    int c = i & 63;
    float mean = stats[c] * (1.0f / NN);
    float var  = stats[64 + c] * (1.0f / NN) - mean * mean;
    float rstd = rsqrtf(var + BN_EPS);
    float v = (h_raw[i] - mean) * rstd * g[c] + be[c];
    out[i] = fmaxf(v, 0.0f);
}

// ---------------- final linear: (N,64) @ (64,10) + b ----------------
__global__ __launch_bounds__(256) void final_linear_kernel(
    const float* __restrict__ h, const float* __restrict__ w,
    const float* __restrict__ b, float* __restrict__ out)
{
    __shared__ float s_w[640];
    __shared__ float s_b[10];
    for (int i = threadIdx.x; i < 640; i += 256) s_w[i] = w[i];
    if (threadIdx.x < 10) s_b[threadIdx.x] = b[threadIdx.x];
    __syncthreads();
    int row = blockIdx.x * 256 + threadIdx.x;
    if (row >= NN) return;
    float acc[10];
    #pragma unroll
    for (int c = 0; c < 10; c++) acc[c] = s_b[c];
    const float* hr = h + row * 64;
    #pragma unroll 4
    for (int k = 0; k < 64; k++) {
        float v = hr[k];
        #pragma unroll
        for (int c = 0; c < 10; c++) acc[c] = fmaf(v, s_w[k * 10 + c], acc[c]);
    }
    #pragma unroll
    for (int c = 0; c < 10; c++) out[row * 10 + c] = acc[c];
}

extern "C" void kernel_launch(void* const* d_in, const int* in_sizes, int n_in,
                              void* d_out, int out_size, void* d_ws, size_t ws_size,
                              hipStream_t stream)
{
    const float* x   = (const float*)d_in[0];
    const int*   ei  = (const int*)d_in[1];
    const int E = in_sizes[1] / 2;

    // per-layer params: base index 2 + 7*i : eps, wa, ba, wb, bb, g, be
    const float* eps[3]; const float* wa[3]; const float* ba[3];
    const float* wb[3];  const float* bb[3]; const float* g[3]; const float* be[3];
    for (int i = 0; i < 3; i++) {
        int base = 2 + 7 * i;
        eps[i] = (const float*)d_in[base + 0];
        wa[i]  = (const float*)d_in[base + 1];
        ba[i]  = (const float*)d_in[base + 2];
        wb[i]  = (const float*)d_in[base + 3];
        bb[i]  = (const float*)d_in[base + 4];
        g[i]   = (const float*)d_in[base + 5];
        be[i]  = (const float*)d_in[base + 6];
    }
    const float* lin_w = (const float*)d_in[23];
    const float* lin_b = (const float*)d_in[24];
    float* out = (float*)d_out;

    // workspace layout (floats)
    float* ws    = (float*)d_ws;
    float* agg   = ws;                       // N*128 (max)
    float* h_raw = agg   + (size_t)NN * 128; // N*64
    float* xA    = h_raw + (size_t)NN * 64;  // N*64
    float* xB    = xA    + (size_t)NN * 64;  // N*64
    float* stats = xB    + (size_t)NN * 64;  // 128

    const float* cur = x;          // layer input
    float* nxt[3] = {xA, xB, xA};  // layer outputs (ping-pong)

    for (int l = 0; l < 3; l++) {
        const int F = (l == 0) ? 128 : 64;
        // zero agg + stats
        hipMemsetAsync(agg, 0, (size_t)NN * F * sizeof(float), stream);
        hipMemsetAsync(stats, 0, 128 * sizeof(float), stream);
        // scatter-add
        if (F == 128) {
            int total = E * 32;
            scatter_add_kernel<5><<<(total + 255) / 256, 256, 0, stream>>>(cur, ei, agg, E);
        } else {
            int total = E * 16;
            scatter_add_kernel<4><<<(total + 255) / 256, 256, 0, stream>>>(cur, ei, agg, E);
        }
        // fused MLP + BN stats
        if (F == 128) {
            gin_mlp_kernel<128><<<2048, 256, 0, stream>>>(cur, agg, eps[l], wa[l], ba[l],
                                                          wb[l], bb[l], h_raw, stats);
        } else {
            gin_mlp_kernel<64><<<2048, 256, 0, stream>>>(cur, agg, eps[l], wa[l], ba[l],
                                                         wb[l], bb[l], h_raw, stats);
        }
        // BN apply + ReLU
        bn_relu_kernel<<<(NN * 64) / 256, 256, 0, stream>>>(h_raw, stats, g[l], be[l], nxt[l]);
        cur = nxt[l];
    }

    // final linear
    final_linear_kernel<<<(NN + 255) / 256, 256, 0, stream>>>(cur, lin_w, lin_b, out);
}

// Round 2
// 939.319 us; speedup vs baseline: 3.2861x; 3.2861x over previous
//
#include <hip/hip_runtime.h>

#define NN 50000
#define BN_EPS 1e-5f

// ================= CSR build (by dst) =================
__global__ __launch_bounds__(256) void hist_kernel(
    const int* __restrict__ ei, int* __restrict__ deg, int E)
{
    int e = blockIdx.x * 256 + threadIdx.x;
    if (e < E) atomicAdd(&deg[ei[E + e]], 1);
}

// single-block exclusive scan of deg[0..NN) -> rowPtr, cursor; rowPtr[NN]=E
__global__ __launch_bounds__(1024) void scan_kernel(
    const int* __restrict__ deg, int* __restrict__ rowPtr, int* __restrict__ cursor)
{
    __shared__ int wsum[16];
    __shared__ int s_carry;
    const int lane = threadIdx.x & 63;
    const int wid  = threadIdx.x >> 6;
    if (threadIdx.x == 0) s_carry = 0;
    __syncthreads();
    for (int base = 0; base < NN; base += 1024) {
        int i = base + threadIdx.x;
        int v = (i < NN) ? deg[i] : 0;
        int incl = v;
        #pragma unroll
        for (int off = 1; off < 64; off <<= 1) {
            int t = __shfl_up(incl, off, 64);
            if (lane >= off) incl += t;
        }
        if (lane == 63) wsum[wid] = incl;
        __syncthreads();
        if (wid == 0) {
            int wv = (lane < 16) ? wsum[lane] : 0;
            int wincl = wv;
            #pragma unroll
            for (int off = 1; off < 16; off <<= 1) {
                int t = __shfl_up(wincl, off, 64);
                if (lane >= off) wincl += t;
            }
            if (lane < 16) wsum[lane] = wincl - wv;  // exclusive wave offset
        }
        __syncthreads();
        int excl = incl - v + wsum[wid] + s_carry;
        if (i < NN) { rowPtr[i] = excl; cursor[i] = excl; }
        __syncthreads();
        if (threadIdx.x == 1023) s_carry = excl + v;  // running total
        __syncthreads();
    }
    if (threadIdx.x == 0) rowPtr[NN] = s_carry;
}

__global__ __launch_bounds__(256) void fill_csr_kernel(
    const int* __restrict__ ei, int* __restrict__ cursor,
    int* __restrict__ csr_src, int E)
{
    int e = blockIdx.x * 256 + threadIdx.x;
    if (e < E) {
        int pos = atomicAdd(&cursor[ei[E + e]], 1);
        csr_src[pos] = ei[e];
    }
}

// ===== fused: CSR-gather agg + (1+eps)*x -> Linear-ReLU-Linear-ReLU + BN stats =====
// Block = 256 threads = 4 rows x 64 cols (one wave per row). Weights in LDS.
template<int F>
__global__ __launch_bounds__(256) void gin_mlp_kernel(
    const float* __restrict__ x,
    const int* __restrict__ rowPtr, const int* __restrict__ csr_src,
    const float* __restrict__ eps_p,
    const float* __restrict__ wa, const float* __restrict__ ba,
    const float* __restrict__ wb, const float* __restrict__ bb,
    float* __restrict__ h_raw, float* __restrict__ stats /*[0:64]=sum [64:128]=sumsq*/)
{
    __shared__ float s_wa[F * 64];
    __shared__ float s_wb[64 * 64];
    __shared__ float s_h[4][F];
    __shared__ float s_t[4][64];

    for (int i = threadIdx.x; i < F * 64; i += 256) s_wa[i] = wa[i];
    for (int i = threadIdx.x; i < 64 * 64; i += 256) s_wb[i] = wb[i];

    const float eps1 = 1.0f + eps_p[0];
    const int r = threadIdx.x >> 6;   // 0..3 (wave id = row within group)
    const int c = threadIdx.x & 63;   // 0..63
    const float ba_c = ba[c];
    const float bb_c = bb[c];
    float sum = 0.0f, sumsq = 0.0f;
    __syncthreads();

    for (int row0 = blockIdx.x * 4; row0 < NN; row0 += gridDim.x * 4) {
        __syncthreads();  // protect s_h/s_t reuse
        // gather: agg + (1+eps)*x, thread owns (row0+r, c [, c+64])
        {
            int row = row0 + r;
            int beg = rowPtr[row], end = rowPtr[row + 1];
            float a0 = eps1 * x[row * F + c];
            float a1 = 0.0f;
            if (F == 128) a1 = eps1 * x[row * F + c + 64];
            for (int e = beg; e < end; e++) {
                int s = csr_src[e];
                a0 += x[s * F + c];
                if (F == 128) a1 += x[s * F + c + 64];
            }
            s_h[r][c] = a0;
            if (F == 128) s_h[r][c + 64] = a1;
        }
        __syncthreads();
        // GEMM1 + ReLU
        float acc = ba_c;
        #pragma unroll 8
        for (int k = 0; k < F; k++)
            acc = fmaf(s_h[r][k], s_wa[k * 64 + c], acc);
        s_t[r][c] = fmaxf(acc, 0.0f);
        __syncthreads();
        // GEMM2 + ReLU
        float acc2 = bb_c;
        #pragma unroll 8
        for (int k = 0; k < 64; k++)
            acc2 = fmaf(s_t[r][k], s_wb[k * 64 + c], acc2);
        float h = fmaxf(acc2, 0.0f);
        h_raw[row0 * 64 + r * 64 + c] = h;
        sum += h;
        sumsq += h * h;
    }

    // BN partial reduction: 2 atomics per column per block
    __syncthreads();
    s_t[r][c] = sum;
    __syncthreads();
    if (r == 0) atomicAdd(&stats[c], s_t[0][c] + s_t[1][c] + s_t[2][c] + s_t[3][c]);
    __syncthreads();
    s_t[r][c] = sumsq;
    __syncthreads();
    if (r == 0) atomicAdd(&stats[64 + c], s_t[0][c] + s_t[1][c] + s_t[2][c] + s_t[3][c]);
}

// ---------------- BN apply + ReLU ----------------
__global__ __launch_bounds__(256) void bn_relu_kernel(
    const float* __restrict__ h_raw, const float* __restrict__ stats,
    const float* __restrict__ g, const float* __restrict__ be,
    float* __restrict__ out)
{
    int i = blockIdx.x * 256 + threadIdx.x;
    int c = i & 63;
    float mean = stats[c] * (1.0f / NN);
    float var  = stats[64 + c] * (1.0f / NN) - mean * mean;
    float rstd = rsqrtf(var + BN_EPS);
    float v = (h_raw[i] - mean) * rstd * g[c] + be[c];
    out[i] = fmaxf(v, 0.0f);
}

// ---------------- final linear: (N,64) @ (64,10) + b ----------------
__global__ __launch_bounds__(256) void final_linear_kernel(
    const float* __restrict__ h, const float* __restrict__ w,
    const float* __restrict__ b, float* __restrict__ out)
{
    __shared__ float s_w[640];
    __shared__ float s_b[10];
    for (int i = threadIdx.x; i < 640; i += 256) s_w[i] = w[i];
    if (threadIdx.x < 10) s_b[threadIdx.x] = b[threadIdx.x];
    __syncthreads();
    int row = blockIdx.x * 256 + threadIdx.x;
    if (row >= NN) return;
    float acc[10];
    #pragma unroll
    for (int c = 0; c < 10; c++) acc[c] = s_b[c];
    const float* hr = h + row * 64;
    #pragma unroll 4
    for (int k = 0; k < 64; k++) {
        float v = hr[k];
        #pragma unroll
        for (int c = 0; c < 10; c++) acc[c] = fmaf(v, s_w[k * 10 + c], acc[c]);
    }
    #pragma unroll
    for (int c = 0; c < 10; c++) out[row * 10 + c] = acc[c];
}

extern "C" void kernel_launch(void* const* d_in, const int* in_sizes, int n_in,
                              void* d_out, int out_size, void* d_ws, size_t ws_size,
                              hipStream_t stream)
{
    const float* x   = (const float*)d_in[0];
    const int*   ei  = (const int*)d_in[1];
    const int E = in_sizes[1] / 2;

    const float* eps[3]; const float* wa[3]; const float* ba[3];
    const float* wb[3];  const float* bb[3]; const float* g[3]; const float* be[3];
    for (int i = 0; i < 3; i++) {
        int base = 2 + 7 * i;
        eps[i] = (const float*)d_in[base + 0];
        wa[i]  = (const float*)d_in[base + 1];
        ba[i]  = (const float*)d_in[base + 2];
        wb[i]  = (const float*)d_in[base + 3];
        bb[i]  = (const float*)d_in[base + 4];
        g[i]   = (const float*)d_in[base + 5];
        be[i]  = (const float*)d_in[base + 6];
    }
    const float* lin_w = (const float*)d_in[23];
    const float* lin_b = (const float*)d_in[24];
    float* out = (float*)d_out;

    // workspace layout
    int*   iws    = (int*)d_ws;
    int*   deg    = iws;                 // NN  (doubles as rowPtr src before scan)
    int*   rowPtr = deg + NN;            // NN+1
    int*   cursor = rowPtr + NN + 1;     // NN
    int*   csrsrc = cursor + NN;         // E
    float* fws    = (float*)(csrsrc + E);
    float* h_raw  = fws;                 // NN*64
    float* xA     = h_raw + (size_t)NN * 64;  // NN*64
    float* xB     = xA    + (size_t)NN * 64;  // NN*64
    float* stats  = xB    + (size_t)NN * 64;  // 128

    // ---- CSR build (once; graph shared by all 3 layers) ----
    hipMemsetAsync(deg, 0, NN * sizeof(int), stream);
    hist_kernel<<<(E + 255) / 256, 256, 0, stream>>>(ei, deg, E);
    scan_kernel<<<1, 1024, 0, stream>>>(deg, rowPtr, cursor);
    fill_csr_kernel<<<(E + 255) / 256, 256, 0, stream>>>(ei, cursor, csrsrc, E);

    const float* cur = x;
    float* nxt[3] = {xA, xB, xA};

    for (int l = 0; l < 3; l++) {
        const int F = (l == 0) ? 128 : 64;
        hipMemsetAsync(stats, 0, 128 * sizeof(float), stream);
        if (F == 128) {
            gin_mlp_kernel<128><<<2048, 256, 0, stream>>>(cur, rowPtr, csrsrc, eps[l],
                wa[l], ba[l], wb[l], bb[l], h_raw, stats);
        } else {
            gin_mlp_kernel<64><<<2048, 256, 0, stream>>>(cur, rowPtr, csrsrc, eps[l],
                wa[l], ba[l], wb[l], bb[l], h_raw, stats);
        }
        bn_relu_kernel<<<(NN * 64) / 256, 256, 0, stream>>>(h_raw, stats, g[l], be[l], nxt[l]);
        cur = nxt[l];
    }

    final_linear_kernel<<<(NN + 255) / 256, 256, 0, stream>>>(cur, lin_w, lin_b, out);
}

// Round 3
// 440.607 us; speedup vs baseline: 7.0055x; 2.1319x over previous
//
#include <hip/hip_runtime.h>

#define NN 50000
#define BN_EPS 1e-5f

// ================= CSR build (by dst) =================
__global__ __launch_bounds__(256) void hist_kernel(
    const int* __restrict__ ei, int* __restrict__ deg, int E)
{
    int e = blockIdx.x * 256 + threadIdx.x;
    if (e < E) atomicAdd(&deg[ei[E + e]], 1);
}

// phase1: per-256-chunk sums
__global__ __launch_bounds__(256) void bsum_kernel(
    const int* __restrict__ deg, int* __restrict__ bsum)
{
    int i = blockIdx.x * 256 + threadIdx.x;
    int v = (i < NN) ? deg[i] : 0;
    #pragma unroll
    for (int off = 32; off >= 1; off >>= 1) v += __shfl_down(v, off, 64);
    __shared__ int ws[4];
    int lane = threadIdx.x & 63, wid = threadIdx.x >> 6;
    if (lane == 0) ws[wid] = v;
    __syncthreads();
    if (threadIdx.x == 0) bsum[blockIdx.x] = ws[0] + ws[1] + ws[2] + ws[3];
}

// phase2: exclusive scan of bsum[NB] (NB<=256) in place; rowPtr[NN]=E
__global__ __launch_bounds__(256) void bscan_kernel(
    int* __restrict__ bsum, int* __restrict__ rowPtr, int NB, int E)
{
    int lane = threadIdx.x & 63, wid = threadIdx.x >> 6;
    int v = (threadIdx.x < NB) ? bsum[threadIdx.x] : 0;
    int incl = v;
    #pragma unroll
    for (int off = 1; off < 64; off <<= 1) {
        int t = __shfl_up(incl, off, 64);
        if (lane >= off) incl += t;
    }
    __shared__ int ws[4];
    if (lane == 63) ws[wid] = incl;
    __syncthreads();
    int woff = 0;
    if (wid > 0) woff += ws[0];
    if (wid > 1) woff += ws[1];
    if (wid > 2) woff += ws[2];
    if (threadIdx.x < NB) bsum[threadIdx.x] = incl - v + woff;
    if (threadIdx.x == 0) rowPtr[NN] = E;
}

// phase3: per-chunk scan + chunk offset -> rowPtr, cursor
__global__ __launch_bounds__(256) void scan_apply_kernel(
    const int* __restrict__ deg, const int* __restrict__ bsum,
    int* __restrict__ rowPtr, int* __restrict__ cursor)
{
    int i = blockIdx.x * 256 + threadIdx.x;
    int lane = threadIdx.x & 63, wid = threadIdx.x >> 6;
    int v = (i < NN) ? deg[i] : 0;
    int incl = v;
    #pragma unroll
    for (int off = 1; off < 64; off <<= 1) {
        int t = __shfl_up(incl, off, 64);
        if (lane >= off) incl += t;
    }
    __shared__ int ws[4];
    if (lane == 63) ws[wid] = incl;
    __syncthreads();
    int woff = bsum[blockIdx.x];
    if (wid > 0) woff += ws[0];
    if (wid > 1) woff += ws[1];
    if (wid > 2) woff += ws[2];
    int excl = incl - v + woff;
    if (i < NN) { rowPtr[i] = excl; cursor[i] = excl; }
}

__global__ __launch_bounds__(256) void fill_csr_kernel(
    const int* __restrict__ ei, int* __restrict__ cursor,
    int* __restrict__ csr_src, int E)
{
    int e = blockIdx.x * 256 + threadIdx.x;
    if (e < E) {
        int pos = atomicAdd(&cursor[ei[E + e]], 1);
        csr_src[pos] = ei[e];
    }
}

// ===== fused: [BN+ReLU of prev layer] + CSR-gather + (1+eps)*self -> MLP + BN stats =====
// 512 threads = 8 waves; each wave owns one row at a time (wave-private s_h[w], NO barriers
// in the main loop). Gather is float4 with EPW edges packed per wave issue.
template<int F, bool APPLY>
__global__ __launch_bounds__(512, 6) void gin_mlp_kernel(
    const float* __restrict__ xin,
    const float* __restrict__ stats_in, const float* __restrict__ g_in,
    const float* __restrict__ be_in,
    const int* __restrict__ rowPtr, const int* __restrict__ csr_src,
    const float* __restrict__ eps_p,
    const float* __restrict__ wa, const float* __restrict__ ba,
    const float* __restrict__ wb, const float* __restrict__ bb,
    float* __restrict__ h_raw, float* __restrict__ stats_out)
{
    constexpr int C4  = F / 4;      // float4 chunks per row (32 or 16)
    constexpr int EPW = 64 / C4;    // edges per wave issue (2 or 4)

    __shared__ float s_wa[F * 64];
    __shared__ float s_wb[64 * 64];
    __shared__ float s_h[8][F];

    for (int i = threadIdx.x; i < F * 64; i += 512) s_wa[i] = wa[i];
    for (int i = threadIdx.x; i < 64 * 64; i += 512) s_wb[i] = wb[i];

    const int w    = threadIdx.x >> 6;
    const int lane = threadIdx.x & 63;
    const int gph  = lane / C4;     // edge slot
    const int cc   = lane % C4;     // float4 chunk within row
    const float eps1 = 1.0f + eps_p[0];
    const float ba_c = ba[lane];
    const float bb_c = bb[lane];

    // BN affine of PREVIOUS layer for this lane's 4 gather columns
    float4 sc = {1.f, 1.f, 1.f, 1.f}, sh = {0.f, 0.f, 0.f, 0.f};
    if (APPLY) {
        int c0 = 4 * cc;
        float* scp = &sc.x; float* shp = &sh.x;
        #pragma unroll
        for (int j = 0; j < 4; j++) {
            float mean = stats_in[c0 + j] * (1.0f / NN);
            float var  = stats_in[64 + c0 + j] * (1.0f / NN) - mean * mean;
            float rstd = rsqrtf(var + BN_EPS);
            float s    = rstd * g_in[c0 + j];
            scp[j] = s;
            shp[j] = be_in[c0 + j] - mean * s;
        }
    }
    __syncthreads();  // weights staged

    float sum = 0.0f, sumsq = 0.0f;
    const float4* x4 = (const float4*)xin;
    const int stride = gridDim.x * 8;

    for (int row = blockIdx.x * 8 + w; row < NN; row += stride) {
        int beg = rowPtr[row], end = rowPtr[row + 1];
        float4 a = {0.f, 0.f, 0.f, 0.f};
        if (gph == 0) {   // self term
            float4 v = x4[row * C4 + cc];
            if (APPLY) {
                v.x = fmaxf(fmaf(v.x, sc.x, sh.x), 0.f);
                v.y = fmaxf(fmaf(v.y, sc.y, sh.y), 0.f);
                v.z = fmaxf(fmaf(v.z, sc.z, sh.z), 0.f);
                v.w = fmaxf(fmaf(v.w, sc.w, sh.w), 0.f);
            }
            a.x = eps1 * v.x; a.y = eps1 * v.y; a.z = eps1 * v.z; a.w = eps1 * v.w;
        }
        #pragma unroll 2
        for (int e = beg + gph; e < end; e += EPW) {
            int s = csr_src[e];
            float4 v = x4[s * C4 + cc];
            if (APPLY) {
                v.x = fmaxf(fmaf(v.x, sc.x, sh.x), 0.f);
                v.y = fmaxf(fmaf(v.y, sc.y, sh.y), 0.f);
                v.z = fmaxf(fmaf(v.z, sc.z, sh.z), 0.f);
                v.w = fmaxf(fmaf(v.w, sc.w, sh.w), 0.f);
            }
            a.x += v.x; a.y += v.y; a.z += v.z; a.w += v.w;
        }
        // reduce across edge slots
        #pragma unroll
        for (int off = C4; off < 64; off <<= 1) {
            a.x += __shfl_xor(a.x, off, 64);
            a.y += __shfl_xor(a.y, off, 64);
            a.z += __shfl_xor(a.z, off, 64);
            a.w += __shfl_xor(a.w, off, 64);
        }
        if (gph == 0) ((float4*)(&s_h[w][0]))[cc] = a;   // wave-private
        // GEMM1 + ReLU (wave-private LDS, in-order DS => no barrier)
        float acc = ba_c;
        #pragma unroll 8
        for (int k = 0; k < F; k++)
            acc = fmaf(s_h[w][k], s_wa[k * 64 + lane], acc);
        float t = fmaxf(acc, 0.0f);
        s_h[w][lane] = t;
        // GEMM2 + ReLU
        float acc2 = bb_c;
        #pragma unroll 8
        for (int k = 0; k < 64; k++)
            acc2 = fmaf(s_h[w][k], s_wb[k * 64 + lane], acc2);
        float h = fmaxf(acc2, 0.0f);
        h_raw[row * 64 + lane] = h;
        sum += h;
        sumsq += h * h;
    }

    // block BN-stat reduction (reuse s_h; needs barriers)
    __syncthreads();
    s_h[w][lane] = sum;
    __syncthreads();
    if (w == 0) {
        float s = 0;
        #pragma unroll
        for (int j = 0; j < 8; j++) s += s_h[j][lane];
        atomicAdd(&stats_out[lane], s);
    }
    __syncthreads();
    s_h[w][lane] = sumsq;
    __syncthreads();
    if (w == 0) {
        float s = 0;
        #pragma unroll
        for (int j = 0; j < 8; j++) s += s_h[j][lane];
        atomicAdd(&stats_out[64 + lane], s);
    }
}

// ---------------- final: BN+ReLU of layer 3, then (N,64)@(64,10)+b ----------------
__global__ __launch_bounds__(256) void final_linear_kernel(
    const float* __restrict__ h, const float* __restrict__ stats,
    const float* __restrict__ g, const float* __restrict__ be,
    const float* __restrict__ w, const float* __restrict__ b,
    float* __restrict__ out)
{
    __shared__ float s_w[640];
    __shared__ float s_b[10];
    __shared__ float s_scale[64];
    __shared__ float s_shift[64];
    for (int i = threadIdx.x; i < 640; i += 256) s_w[i] = w[i];
    if (threadIdx.x < 10) s_b[threadIdx.x] = b[threadIdx.x];
    if (threadIdx.x < 64) {
        int c = threadIdx.x;
        float mean = stats[c] * (1.0f / NN);
        float var  = stats[64 + c] * (1.0f / NN) - mean * mean;
        float rstd = rsqrtf(var + BN_EPS);
        float s    = rstd * g[c];
        s_scale[c] = s;
        s_shift[c] = be[c] - mean * s;
    }
    __syncthreads();
    int row = blockIdx.x * 256 + threadIdx.x;
    if (row >= NN) return;
    float acc[10];
    #pragma unroll
    for (int c = 0; c < 10; c++) acc[c] = s_b[c];
    const float* hr = h + row * 64;
    #pragma unroll 4
    for (int k = 0; k < 64; k++) {
        float v = fmaxf(fmaf(hr[k], s_scale[k], s_shift[k]), 0.0f);
        #pragma unroll
        for (int c = 0; c < 10; c++) acc[c] = fmaf(v, s_w[k * 10 + c], acc[c]);
    }
    #pragma unroll
    for (int c = 0; c < 10; c++) out[row * 10 + c] = acc[c];
}

extern "C" void kernel_launch(void* const* d_in, const int* in_sizes, int n_in,
                              void* d_out, int out_size, void* d_ws, size_t ws_size,
                              hipStream_t stream)
{
    const float* x  = (const float*)d_in[0];
    const int*   ei = (const int*)d_in[1];
    const int E = in_sizes[1] / 2;

    const float* eps[3]; const float* wa[3]; const float* ba[3];
    const float* wb[3];  const float* bb[3]; const float* g[3]; const float* be[3];
    for (int i = 0; i < 3; i++) {
        int base = 2 + 7 * i;
        eps[i] = (const float*)d_in[base + 0];
        wa[i]  = (const float*)d_in[base + 1];
        ba[i]  = (const float*)d_in[base + 2];
        wb[i]  = (const float*)d_in[base + 3];
        bb[i]  = (const float*)d_in[base + 4];
        g[i]   = (const float*)d_in[base + 5];
        be[i]  = (const float*)d_in[base + 6];
    }
    const float* lin_w = (const float*)d_in[23];
    const float* lin_b = (const float*)d_in[24];
    float* out = (float*)d_out;

    // workspace layout
    const int NB = (NN + 255) / 256;         // 196 scan chunks
    int*   iws    = (int*)d_ws;
    int*   deg    = iws;                      // NN
    int*   rowPtr = deg + NN;                 // NN+1
    int*   cursor = rowPtr + NN + 1;          // NN
    int*   bsum   = cursor + NN;              // 256
    int*   csrsrc = bsum + 256;               // E
    float* fws    = (float*)(csrsrc + E);
    float* hA     = fws;                      // NN*64
    float* hB     = hA + (size_t)NN * 64;     // NN*64
    float* stats  = hB + (size_t)NN * 64;     // 3*128

    // ---- CSR build ----
    hipMemsetAsync(deg, 0, NN * sizeof(int), stream);
    hipMemsetAsync(stats, 0, 3 * 128 * sizeof(float), stream);
    hist_kernel<<<(E + 255) / 256, 256, 0, stream>>>(ei, deg, E);
    bsum_kernel<<<NB, 256, 0, stream>>>(deg, bsum);
    bscan_kernel<<<1, 256, 0, stream>>>(bsum, rowPtr, NB, E);
    scan_apply_kernel<<<NB, 256, 0, stream>>>(deg, bsum, rowPtr, cursor);
    fill_csr_kernel<<<(E + 255) / 256, 256, 0, stream>>>(ei, cursor, csrsrc, E);

    // ---- layer 1 (F=128, raw x input) ----
    gin_mlp_kernel<128, false><<<768, 512, 0, stream>>>(
        x, nullptr, nullptr, nullptr, rowPtr, csrsrc, eps[0],
        wa[0], ba[0], wb[0], bb[0], hA, stats);
    // ---- layer 2 (F=64, BN1+ReLU fused into gather) ----
    gin_mlp_kernel<64, true><<<1024, 512, 0, stream>>>(
        hA, stats, g[0], be[0], rowPtr, csrsrc, eps[1],
        wa[1], ba[1], wb[1], bb[1], hB, stats + 128);
    // ---- layer 3 (F=64, BN2+ReLU fused) ----
    gin_mlp_kernel<64, true><<<1024, 512, 0, stream>>>(
        hB, stats + 128, g[1], be[1], rowPtr, csrsrc, eps[2],
        wa[2], ba[2], wb[2], bb[2], hA, stats + 256);
    // ---- final linear with BN3+ReLU fused ----
    final_linear_kernel<<<(NN + 255) / 256, 256, 0, stream>>>(
        hA, stats + 256, g[2], be[2], lin_w, lin_b, out);
}